// Round 7
// baseline (182.044 us; speedup 1.0000x reference)
//
#include <hip/hip_runtime.h>
#include <stdint.h>

// Problem constants (B,C,H,W = 8,256,48,48)
#define NB  8
#define NC  256
#define NCR 32
#define NSP 2304  // N = H*W

typedef __attribute__((ext_vector_type(8))) short short8;   // 8 x bf16 (4 VGPRs)
typedef __attribute__((ext_vector_type(4))) float f32x4;    // MFMA C/D frag
typedef __attribute__((ext_vector_type(4))) unsigned short us4;

__device__ __forceinline__ unsigned short f2bf(float f) {
  union { float f; unsigned u; } a; a.f = f;
  unsigned r = (a.u + 0x7FFFu + ((a.u >> 16) & 1u)) >> 16;  // RNE
  return (unsigned short)r;
}

typedef __attribute__((address_space(1))) const void* gvoidp;
typedef __attribute__((address_space(3))) void* lvoidp;
#define GLOADLDS16(g, l) __builtin_amdgcn_global_load_lds((gvoidp)(g), (lvoidp)(l), 16, 0, 0)

// ---------------------------------------------------------------------------
// Kernel 1 (fused transpose + QKV projection) — UNCHANGED (proven R5/R6).
__global__ __launch_bounds__(256) void k_proj(const float* __restrict__ x,
    const float* __restrict__ w1, const float* __restrict__ b1,
    const float* __restrict__ w2, const float* __restrict__ b2,
    const float* __restrict__ w3, const float* __restrict__ b3,
    unsigned short* __restrict__ Q, unsigned short* __restrict__ K,
    unsigned short* __restrict__ V) {
  __shared__ unsigned short xs[32][264];  // [n][c], +8 pad
  const int n0 = blockIdx.x * 32, b = blockIdx.y;
  const int t = threadIdx.x, lane = t & 63, wave = t >> 6;
  const int col = lane & 15, quad = lane >> 4;
  const float* xb = x + (size_t)b * NC * NSP;
#pragma unroll
  for (int p = 0; p < 8; ++p) {
    const int crow = (t >> 3) + p * 32;     // 0..255
    const int n4 = (t & 7) * 4;             // 0..28
    float4 v = *(const float4*)(xb + (size_t)crow * NSP + n0 + n4);
    xs[n4 + 0][crow] = f2bf(v.x);
    xs[n4 + 1][crow] = f2bf(v.y);
    xs[n4 + 2][crow] = f2bf(v.z);
    xs[n4 + 3][crow] = f2bf(v.w);
  }
  __syncthreads();
  const f32x4 zero4 = {0.f, 0.f, 0.f, 0.f};
  f32x4 acc[5][2];
#pragma unroll
  for (int i = 0; i < 5; ++i)
#pragma unroll
    for (int j = 0; j < 2; ++j) acc[i][j] = zero4;

  for (int kc = 0; kc < 8; ++kc) {
    short8 bf[2];
#pragma unroll
    for (int nt = 0; nt < 2; ++nt)
      bf[nt] = *(const short8*)&xs[nt * 16 + col][kc * 32 + quad * 8];
#pragma unroll
    for (int ml = 0; ml < 5; ++ml) {
      const int m0 = (wave * 5 + ml) * 16;
      const float* wbase; int roff;
      if (m0 < 32)      { wbase = w1; roff = m0; }
      else if (m0 < 64) { wbase = w2; roff = m0 - 32; }
      else              { wbase = w3; roff = m0 - 64; }
      const float* wp = wbase + (size_t)(roff + col) * NC + kc * 32 + quad * 8;
      float4 f0 = *(const float4*)wp;
      float4 f1 = *(const float4*)(wp + 4);
      short8 af;
      af[0] = f2bf(f0.x); af[1] = f2bf(f0.y); af[2] = f2bf(f0.z); af[3] = f2bf(f0.w);
      af[4] = f2bf(f1.x); af[5] = f2bf(f1.y); af[6] = f2bf(f1.z); af[7] = f2bf(f1.w);
#pragma unroll
      for (int nt = 0; nt < 2; ++nt)
        acc[ml][nt] = __builtin_amdgcn_mfma_f32_16x16x32_bf16(af, bf[nt], acc[ml][nt], 0, 0, 0);
    }
  }
#pragma unroll
  for (int ml = 0; ml < 5; ++ml) {
    const int m0 = (wave * 5 + ml) * 16;
    const float* bias;
    if (m0 < 32)      bias = b1 + m0;
    else if (m0 < 64) bias = b2 + (m0 - 32);
    else              bias = b3 + (m0 - 64);
    float bv[4];
#pragma unroll
    for (int r = 0; r < 4; ++r) bv[r] = bias[quad * 4 + r];
    if (m0 < 64) {  // Q or K : [b][n][32]
      unsigned short* dst = (m0 < 32) ? Q : K;
      const int d0 = (m0 & 31) + quad * 4;
#pragma unroll
      for (int nt = 0; nt < 2; ++nt) {
        const int n = n0 + nt * 16 + col;
        us4 pk;
#pragma unroll
        for (int r = 0; r < 4; ++r) pk[r] = f2bf(acc[ml][nt][r] + bv[r]);
        *(us4*)(dst + ((size_t)b * NSP + n) * NCR + d0) = pk;
      }
    } else {        // V : [b][c][n]
      const int cbase = m0 - 64 + quad * 4;
#pragma unroll
      for (int nt = 0; nt < 2; ++nt) {
        const int n = n0 + nt * 16 + col;
#pragma unroll
        for (int r = 0; r < 4; ++r)
          V[((size_t)b * NC + cbase + r) * NSP + n] = f2bf(acc[ml][nt][r] + bv[r]);
      }
    }
  }
}

// ---------------------------------------------------------------------------
// Kernel 2 (fused attention; XOR-swizzled Vs staging + 2x B-frag reuse):
// block = 3 waves x 32 i-rows = 96 rows, c-tile 64. grid (24,4,8)=768 = exactly
// 3 blocks/CU (LDS 44KB), tail-free. Vs rows 128B with 16B-chunk XOR swizzle
// (phys = logical ^ (c&7)) applied on the GLOBAL source side so global_load_lds
// keeps its fixed lane*16 dst; vbf reads become 2-way/bank (free).
// Per iter: barrier -> kb(n+1) -> stage(n+1) -> PV(n) (each vbf feeds 2 MFMAs)
// -> scores(n+1)+exp. No-max softmax exact (logits <= ~30 << 88).
__global__ __launch_bounds__(192) void k_attn(const unsigned short* __restrict__ Q,
    const unsigned short* __restrict__ K, const unsigned short* __restrict__ V,
    const float* __restrict__ feat, const float* __restrict__ gamma,
    float* __restrict__ out) {
  __shared__ __align__(16) unsigned short smem[22016];  // 44032 B
  unsigned short* Vs = smem;           // [buf][64 c][64 j] : 2 x 4096 u16 (rows 128B)
  unsigned short* Ps = smem + 8192;    // [wave][buf][32 i][72] : 3 x 2 x 2304 u16
  const int i0 = blockIdx.x * 96, ch = blockIdx.y * 64, b = blockIdx.z;
  const int t = threadIdx.x, lane = t & 63, wave = t >> 6;  // wave 0..2
  const int col = lane & 15, quad = lane >> 4;
  const int iw = i0 + wave * 32;
  const unsigned short* Qb = Q + (size_t)b * NSP * NCR;
  const unsigned short* Kb = K + (size_t)b * NSP * NCR;
  const unsigned short* Vb = V + (size_t)b * NC * NSP;
  unsigned short* PsW = Ps + wave * 4608;  // 2 bufs x 2304

  short8 qa[2];
#pragma unroll
  for (int it = 0; it < 2; ++it)
    qa[it] = *(const short8*)(Qb + (size_t)(iw + it * 16 + col) * NCR + quad * 8);
  const f32x4 zero4 = {0.f, 0.f, 0.f, 0.f};
  f32x4 acc[2][4];
#pragma unroll
  for (int it = 0; it < 2; ++it)
#pragma unroll
    for (int ct = 0; ct < 4; ++ct) acc[it][ct] = zero4;
  float rs[2][4] = {{0.f,0.f,0.f,0.f},{0.f,0.f,0.f,0.f}};
  // staging lane map: call q covers c-rows q*8..q*8+7; lane -> (row r8, phys chunk pc);
  // phys chunk pc holds logical j-chunk pc ^ (c&7) = pc ^ r8.
  const int r8 = lane >> 3, pc = lane & 7, jcs = pc ^ r8;

  // ---- prologue: kb(0), stage(0) -> buf0, scores(0) -> Ps buf0
  short8 kb[4];
#pragma unroll
  for (int mt = 0; mt < 4; ++mt)
    kb[mt] = *(const short8*)(Kb + (size_t)(mt * 16 + col) * NCR + quad * 8);
#pragma unroll
  for (int cix = 0; cix < 3; ++cix) {
    const int q = wave * 3 + cix;          // 0..8; q==8 skipped (wave-uniform)
    if (q < 8) {
      const unsigned short* g = Vb + (size_t)(ch + q * 8 + r8) * NSP + jcs * 8;
      GLOADLDS16(g, Vs + q * 512);
    }
  }
#pragma unroll
  for (int it = 0; it < 2; ++it)
#pragma unroll
    for (int mt = 0; mt < 4; ++mt) {
      f32x4 s = __builtin_amdgcn_mfma_f32_16x16x32_bf16(qa[it], kb[mt], zero4, 0, 0, 0);
#pragma unroll
      for (int r = 0; r < 4; ++r) {
        const float e = __expf(s[r]);
        rs[it][r] += e;
        PsW[(it * 16 + quad * 4 + r) * 72 + mt * 16 + col] = f2bf(e);
      }
    }

  // ---- main loop: one barrier per iteration
  for (int kc = 0; kc < 36; ++kc) {
    __syncthreads();  // Vs(kc) staged (vmcnt drained), Ps(kc) written
    const int bufc = kc & 1, bufn = bufc ^ 1;
    const int j1 = (kc + 1) * 64;
    const bool more = (kc + 1 < 36);
    if (more) {
      // kb(n+1) first (in-order vmcnt: retires before staging loads)
#pragma unroll
      for (int mt = 0; mt < 4; ++mt)
        kb[mt] = *(const short8*)(Kb + (size_t)(j1 + mt * 16 + col) * NCR + quad * 8);
      // stage(n+1) -> Vs bufn (full PV+scores to drain before next barrier)
#pragma unroll
      for (int cix = 0; cix < 3; ++cix) {
        const int q = wave * 3 + cix;
        if (q < 8) {
          const unsigned short* g = Vb + (size_t)(ch + q * 8 + r8) * NSP + j1 + jcs * 8;
          GLOADLDS16(g, Vs + bufn * 4096 + q * 512);
        }
      }
    }
    // PV(kc): each vbf read feeds 2 MFMAs (i-tile pair)
    const unsigned short* pwc = PsW + bufc * 2304;
    const unsigned short* vsc = Vs + bufc * 4096;
#pragma unroll
    for (int kk = 0; kk < 2; ++kk) {
      short8 pa[2];
#pragma unroll
      for (int it = 0; it < 2; ++it)
        pa[it] = *(const short8*)(pwc + (it * 16 + col) * 72 + kk * 32 + quad * 8);
#pragma unroll
      for (int ct = 0; ct < 4; ++ct) {
        const short8 vbf = *(const short8*)(vsc + (ct * 16 + col) * 64 +
                                            (((kk * 4 + quad) ^ (col & 7)) * 8));
        acc[0][ct] = __builtin_amdgcn_mfma_f32_16x16x32_bf16(pa[0], vbf, acc[0][ct], 0, 0, 0);
        acc[1][ct] = __builtin_amdgcn_mfma_f32_16x16x32_bf16(pa[1], vbf, acc[1][ct], 0, 0, 0);
      }
    }
    if (more) {
      // scores(n+1) -> Ps bufn
      unsigned short* pwn = PsW + bufn * 2304;
#pragma unroll
      for (int it = 0; it < 2; ++it)
#pragma unroll
        for (int mt = 0; mt < 4; ++mt) {
          f32x4 s = __builtin_amdgcn_mfma_f32_16x16x32_bf16(qa[it], kb[mt], zero4, 0, 0, 0);
#pragma unroll
          for (int r = 0; r < 4; ++r) {
            const float e = __expf(s[r]);
            rs[it][r] += e;
            pwn[(it * 16 + quad * 4 + r) * 72 + mt * 16 + col] = f2bf(e);
          }
        }
    }
  }

  // ---- l: butterfly over the 16 cols (j fully reduced in-register)
#pragma unroll
  for (int off = 1; off < 16; off <<= 1)
#pragma unroll
    for (int it = 0; it < 2; ++it)
#pragma unroll
      for (int r = 0; r < 4; ++r) rs[it][r] += __shfl_xor(rs[it][r], off, 64);
  const float g = gamma[0];
  float rinv[2][4];
#pragma unroll
  for (int it = 0; it < 2; ++it)
#pragma unroll
    for (int r = 0; r < 4; ++r) rinv[it][r] = g / rs[it][r];

  // ---- epilogue: float4 over r (i-contiguous), 64B segments
  const float* fb = feat + (size_t)b * NC * NSP;
  float* ob = out + (size_t)b * NC * NSP;
#pragma unroll
  for (int it = 0; it < 2; ++it)
#pragma unroll
    for (int ct = 0; ct < 4; ++ct) {
      const size_t a0 = (size_t)(ch + ct * 16 + col) * NSP + iw + it * 16 + quad * 4;
      float4 f = *(const float4*)(fb + a0);
      float4 o;
      o.x = acc[it][ct][0] * rinv[it][0] + f.x;
      o.y = acc[it][ct][1] * rinv[it][1] + f.y;
      o.z = acc[it][ct][2] * rinv[it][2] + f.z;
      o.w = acc[it][ct][3] * rinv[it][3] + f.w;
      *(float4*)(ob + a0) = o;
    }
}

// ---------------------------------------------------------------------------
// Workspace layout (bytes), total 11,796,480 (~11.3 MB):
//   Q : [0, 1179648)            bf16 [8][2304][32]
//   K : [1179648, 2359296)      bf16 [8][2304][32]
//   V : [2359296, 11796480)     bf16 [8][256][2304]
#define OFF_Q  0UL
#define OFF_K  1179648UL
#define OFF_V  2359296UL

extern "C" void kernel_launch(void* const* d_in, const int* in_sizes, int n_in,
                              void* d_out, int out_size, void* d_ws, size_t ws_size,
                              hipStream_t stream) {
  const float* feat  = (const float*)d_in[0];
  const float* w1    = (const float*)d_in[1];
  const float* b1    = (const float*)d_in[2];
  const float* w2    = (const float*)d_in[3];
  const float* b2    = (const float*)d_in[4];
  const float* w3    = (const float*)d_in[5];
  const float* b3    = (const float*)d_in[6];
  const float* gamma = (const float*)d_in[7];
  float* out = (float*)d_out;
  char* ws = (char*)d_ws;
  unsigned short* Q = (unsigned short*)(ws + OFF_Q);
  unsigned short* K = (unsigned short*)(ws + OFF_K);
  unsigned short* V = (unsigned short*)(ws + OFF_V);

  hipLaunchKernelGGL(k_proj, dim3(72, NB), dim3(256), 0, stream,
                     feat, w1, b1, w2, b2, w3, b3, Q, K, V);
  hipLaunchKernelGGL(k_attn, dim3(24, 4, NB), dim3(192), 0, stream,
                     Q, K, V, feat, gamma, out);
}

// Round 8
// 169.637 us; speedup vs baseline: 1.0731x; 1.0731x over previous
//
#include <hip/hip_runtime.h>
#include <stdint.h>

// Problem constants (B,C,H,W = 8,256,48,48)
#define NB  8
#define NC  256
#define NCR 32
#define NSP 2304  // N = H*W

typedef __attribute__((ext_vector_type(8))) short short8;   // 8 x bf16 (4 VGPRs)
typedef __attribute__((ext_vector_type(4))) float f32x4;    // MFMA C/D frag
typedef __attribute__((ext_vector_type(4))) unsigned short us4;

__device__ __forceinline__ unsigned short f2bf(float f) {
  union { float f; unsigned u; } a; a.f = f;
  unsigned r = (a.u + 0x7FFFu + ((a.u >> 16) & 1u)) >> 16;  // RNE
  return (unsigned short)r;
}

typedef __attribute__((address_space(1))) const void* gvoidp;
typedef __attribute__((address_space(3))) void* lvoidp;
#define GLOADLDS16(g, l) __builtin_amdgcn_global_load_lds((gvoidp)(g), (lvoidp)(l), 16, 0, 0)

// ---------------------------------------------------------------------------
// Kernel 1 (fused transpose + QKV projection) — UNCHANGED (proven R5/R6/R7).
__global__ __launch_bounds__(256) void k_proj(const float* __restrict__ x,
    const float* __restrict__ w1, const float* __restrict__ b1,
    const float* __restrict__ w2, const float* __restrict__ b2,
    const float* __restrict__ w3, const float* __restrict__ b3,
    unsigned short* __restrict__ Q, unsigned short* __restrict__ K,
    unsigned short* __restrict__ V) {
  __shared__ unsigned short xs[32][264];  // [n][c], +8 pad
  const int n0 = blockIdx.x * 32, b = blockIdx.y;
  const int t = threadIdx.x, lane = t & 63, wave = t >> 6;
  const int col = lane & 15, quad = lane >> 4;
  const float* xb = x + (size_t)b * NC * NSP;
#pragma unroll
  for (int p = 0; p < 8; ++p) {
    const int crow = (t >> 3) + p * 32;     // 0..255
    const int n4 = (t & 7) * 4;             // 0..28
    float4 v = *(const float4*)(xb + (size_t)crow * NSP + n0 + n4);
    xs[n4 + 0][crow] = f2bf(v.x);
    xs[n4 + 1][crow] = f2bf(v.y);
    xs[n4 + 2][crow] = f2bf(v.z);
    xs[n4 + 3][crow] = f2bf(v.w);
  }
  __syncthreads();
  const f32x4 zero4 = {0.f, 0.f, 0.f, 0.f};
  f32x4 acc[5][2];
#pragma unroll
  for (int i = 0; i < 5; ++i)
#pragma unroll
    for (int j = 0; j < 2; ++j) acc[i][j] = zero4;

  for (int kc = 0; kc < 8; ++kc) {
    short8 bf[2];
#pragma unroll
    for (int nt = 0; nt < 2; ++nt)
      bf[nt] = *(const short8*)&xs[nt * 16 + col][kc * 32 + quad * 8];
#pragma unroll
    for (int ml = 0; ml < 5; ++ml) {
      const int m0 = (wave * 5 + ml) * 16;
      const float* wbase; int roff;
      if (m0 < 32)      { wbase = w1; roff = m0; }
      else if (m0 < 64) { wbase = w2; roff = m0 - 32; }
      else              { wbase = w3; roff = m0 - 64; }
      const float* wp = wbase + (size_t)(roff + col) * NC + kc * 32 + quad * 8;
      float4 f0 = *(const float4*)wp;
      float4 f1 = *(const float4*)(wp + 4);
      short8 af;
      af[0] = f2bf(f0.x); af[1] = f2bf(f0.y); af[2] = f2bf(f0.z); af[3] = f2bf(f0.w);
      af[4] = f2bf(f1.x); af[5] = f2bf(f1.y); af[6] = f2bf(f1.z); af[7] = f2bf(f1.w);
#pragma unroll
      for (int nt = 0; nt < 2; ++nt)
        acc[ml][nt] = __builtin_amdgcn_mfma_f32_16x16x32_bf16(af, bf[nt], acc[ml][nt], 0, 0, 0);
    }
  }
#pragma unroll
  for (int ml = 0; ml < 5; ++ml) {
    const int m0 = (wave * 5 + ml) * 16;
    const float* bias;
    if (m0 < 32)      bias = b1 + m0;
    else if (m0 < 64) bias = b2 + (m0 - 32);
    else              bias = b3 + (m0 - 64);
    float bv[4];
#pragma unroll
    for (int r = 0; r < 4; ++r) bv[r] = bias[quad * 4 + r];
    if (m0 < 64) {  // Q or K : [b][n][32]
      unsigned short* dst = (m0 < 32) ? Q : K;
      const int d0 = (m0 & 31) + quad * 4;
#pragma unroll
      for (int nt = 0; nt < 2; ++nt) {
        const int n = n0 + nt * 16 + col;
        us4 pk;
#pragma unroll
        for (int r = 0; r < 4; ++r) pk[r] = f2bf(acc[ml][nt][r] + bv[r]);
        *(us4*)(dst + ((size_t)b * NSP + n) * NCR + d0) = pk;
      }
    } else {        // V : [b][c][n]
      const int cbase = m0 - 64 + quad * 4;
#pragma unroll
      for (int nt = 0; nt < 2; ++nt) {
        const int n = n0 + nt * 16 + col;
#pragma unroll
        for (int r = 0; r < 4; ++r)
          V[((size_t)b * NC + cbase + r) * NSP + n] = f2bf(acc[ml][nt][r] + bv[r]);
      }
    }
  }
}

// ---------------------------------------------------------------------------
// Kernel 2 (fused attention = R6 tiling + R7 XOR swizzle):
// block = 48 i-rows (3 waves x 16) x 128 c-half, 192 threads.
// grid (48, 2, 8) = 768 = EXACTLY 3 blocks/CU (LDS 46.6KB), zero tail;
// scores duplication x2 (c-halves) — R7's x4 proved too much VALU.
// Vs rows = 64 j elems (128B); 16B-chunk XOR swizzle phys = logical ^ (c&7)
// applied on the GLOBAL source side (global_load_lds dst stays lane*16);
// vbf reads -> 2 lanes/bank (free, m136). Per iter: barrier -> kb(n+1) ->
// stage(n+1) -> PV(n) -> scores(n+1)+exp (no-max softmax exact, logits<=~30).
__global__ __launch_bounds__(192) void k_attn(const unsigned short* __restrict__ Q,
    const unsigned short* __restrict__ K, const unsigned short* __restrict__ V,
    const float* __restrict__ feat, const float* __restrict__ gamma,
    float* __restrict__ out) {
  __shared__ __align__(16) unsigned short smem[23296];  // 46592 B
  unsigned short* Vs = smem;            // [buf][128 c][64 j] : 2 x 8192 u16
  unsigned short* Ps = smem + 16384;    // [wave][buf][16 i][72] : 3 x 2 x 1152 u16
  const int i0 = blockIdx.x * 48, ch = blockIdx.y * 128, b = blockIdx.z;
  const int t = threadIdx.x, lane = t & 63, wave = t >> 6;  // wave 0..2
  const int col = lane & 15, quad = lane >> 4;
  const int iw = i0 + wave * 16;
  const unsigned short* Qb = Q + (size_t)b * NSP * NCR;
  const unsigned short* Kb = K + (size_t)b * NSP * NCR;
  const unsigned short* Vb = V + (size_t)b * NC * NSP;
  unsigned short* PsW = Ps + wave * 2304;  // 2 bufs x 1152

  const short8 qa = *(const short8*)(Qb + (size_t)(iw + col) * NCR + quad * 8);
  const f32x4 zero4 = {0.f, 0.f, 0.f, 0.f};
  f32x4 acc[8];
#pragma unroll
  for (int ct = 0; ct < 8; ++ct) acc[ct] = zero4;
  float rs[4] = {0.f, 0.f, 0.f, 0.f};
  // staging lane map: call q covers c-rows q*8..q*8+7 (8 rows x 8 chunks of 16B);
  // lane -> row r8 = lane>>3, phys chunk pc = lane&7 holding logical chunk pc^r8.
  const int r8 = lane >> 3, pc = lane & 7, jcs = pc ^ r8;

  // ---- prologue: kb(0), stage(0) -> buf0, scores(0) -> Ps buf0
  short8 kb[4];
#pragma unroll
  for (int mt = 0; mt < 4; ++mt)
    kb[mt] = *(const short8*)(Kb + (size_t)(mt * 16 + col) * NCR + quad * 8);
#pragma unroll
  for (int cix = 0; cix < 6; ++cix) {
    const int q = wave * 6 + cix;          // 0..17; q>=16 skipped (wave-uniform)
    if (q < 16) {
      const unsigned short* g = Vb + (size_t)(ch + q * 8 + r8) * NSP + jcs * 8;
      GLOADLDS16(g, Vs + q * 512);
    }
  }
#pragma unroll
  for (int mt = 0; mt < 4; ++mt) {
    f32x4 s = __builtin_amdgcn_mfma_f32_16x16x32_bf16(qa, kb[mt], zero4, 0, 0, 0);
#pragma unroll
    for (int r = 0; r < 4; ++r) {
      const float e = __expf(s[r]);
      rs[r] += e;
      PsW[(quad * 4 + r) * 72 + mt * 16 + col] = f2bf(e);
    }
  }

  // ---- main loop: one barrier per iteration
  for (int kc = 0; kc < 36; ++kc) {
    __syncthreads();  // Vs(kc) staged (vmcnt drained), Ps(kc) written
    const int bufc = kc & 1, bufn = bufc ^ 1;
    const int j1 = (kc + 1) * 64;
    const bool more = (kc + 1 < 36);
    if (more) {
      // kb(n+1) first (in-order vmcnt: retires before the staging loads)
#pragma unroll
      for (int mt = 0; mt < 4; ++mt)
        kb[mt] = *(const short8*)(Kb + (size_t)(j1 + mt * 16 + col) * NCR + quad * 8);
      // stage(n+1) -> Vs bufn (full PV+scores distance to drain before barrier)
#pragma unroll
      for (int cix = 0; cix < 6; ++cix) {
        const int q = wave * 6 + cix;
        if (q < 16) {
          const unsigned short* g = Vb + (size_t)(ch + q * 8 + r8) * NSP + j1 + jcs * 8;
          GLOADLDS16(g, Vs + bufn * 8192 + q * 512);
        }
      }
    }
    // PV(kc)
    const unsigned short* pwc = PsW + bufc * 1152;
    const unsigned short* vsc = Vs + bufc * 8192;
#pragma unroll
    for (int kk = 0; kk < 2; ++kk) {
      const short8 pa = *(const short8*)(pwc + col * 72 + kk * 32 + quad * 8);
#pragma unroll
      for (int ct = 0; ct < 8; ++ct) {
        const short8 vbf = *(const short8*)(vsc + (ct * 16 + col) * 64 +
                                            (((kk * 4 + quad) ^ (col & 7)) * 8));
        acc[ct] = __builtin_amdgcn_mfma_f32_16x16x32_bf16(pa, vbf, acc[ct], 0, 0, 0);
      }
    }
    if (more) {
      // scores(n+1) -> Ps bufn
      unsigned short* pwn = PsW + bufn * 1152;
#pragma unroll
      for (int mt = 0; mt < 4; ++mt) {
        f32x4 s = __builtin_amdgcn_mfma_f32_16x16x32_bf16(qa, kb[mt], zero4, 0, 0, 0);
#pragma unroll
        for (int r = 0; r < 4; ++r) {
          const float e = __expf(s[r]);
          rs[r] += e;
          pwn[(quad * 4 + r) * 72 + mt * 16 + col] = f2bf(e);
        }
      }
    }
  }

  // ---- l: butterfly over the 16 cols (j fully reduced in-register)
#pragma unroll
  for (int off = 1; off < 16; off <<= 1)
#pragma unroll
    for (int r = 0; r < 4; ++r) rs[r] += __shfl_xor(rs[r], off, 64);
  const float g = gamma[0];
  float rinv[4];
#pragma unroll
  for (int r = 0; r < 4; ++r) rinv[r] = g / rs[r];

  // ---- epilogue: float4 over r (i-contiguous), 64B segments
  const float* fb = feat + (size_t)b * NC * NSP;
  float* ob = out + (size_t)b * NC * NSP;
#pragma unroll
  for (int ct = 0; ct < 8; ++ct) {
    const size_t a0 = (size_t)(ch + ct * 16 + col) * NSP + iw + quad * 4;
    float4 f = *(const float4*)(fb + a0);
    float4 o;
    o.x = acc[ct][0] * rinv[0] + f.x;
    o.y = acc[ct][1] * rinv[1] + f.y;
    o.z = acc[ct][2] * rinv[2] + f.z;
    o.w = acc[ct][3] * rinv[3] + f.w;
    *(float4*)(ob + a0) = o;
  }
}

// ---------------------------------------------------------------------------
// Workspace layout (bytes), total 11,796,480 (~11.3 MB):
//   Q : [0, 1179648)            bf16 [8][2304][32]
//   K : [1179648, 2359296)      bf16 [8][2304][32]
//   V : [2359296, 11796480)     bf16 [8][256][2304]
#define OFF_Q  0UL
#define OFF_K  1179648UL
#define OFF_V  2359296UL

extern "C" void kernel_launch(void* const* d_in, const int* in_sizes, int n_in,
                              void* d_out, int out_size, void* d_ws, size_t ws_size,
                              hipStream_t stream) {
  const float* feat  = (const float*)d_in[0];
  const float* w1    = (const float*)d_in[1];
  const float* b1    = (const float*)d_in[2];
  const float* w2    = (const float*)d_in[3];
  const float* b2    = (const float*)d_in[4];
  const float* w3    = (const float*)d_in[5];
  const float* b3    = (const float*)d_in[6];
  const float* gamma = (const float*)d_in[7];
  float* out = (float*)d_out;
  char* ws = (char*)d_ws;
  unsigned short* Q = (unsigned short*)(ws + OFF_Q);
  unsigned short* K = (unsigned short*)(ws + OFF_K);
  unsigned short* V = (unsigned short*)(ws + OFF_V);

  hipLaunchKernelGGL(k_proj, dim3(72, NB), dim3(256), 0, stream,
                     feat, w1, b1, w2, b2, w3, b3, Q, K, V);
  hipLaunchKernelGGL(k_attn, dim3(48, 2, NB), dim3(192), 0, stream,
                     Q, K, V, feat, gamma, out);
}

// Round 9
// 167.713 us; speedup vs baseline: 1.0854x; 1.0115x over previous
//
#include <hip/hip_runtime.h>
#include <stdint.h>

// Problem constants (B,C,H,W = 8,256,48,48)
#define NB  8
#define NC  256
#define NCR 32
#define NSP 2304  // N = H*W
#define LOG2E 1.44269504088896340736f

typedef __attribute__((ext_vector_type(8))) short short8;   // 8 x bf16 (4 VGPRs)
typedef __attribute__((ext_vector_type(4))) float f32x4;    // MFMA C/D frag
typedef __attribute__((ext_vector_type(4))) unsigned short us4;
typedef __attribute__((ext_vector_type(2))) unsigned int u32x2;

__device__ __forceinline__ unsigned short f2bf(float f) {
  union { float f; unsigned u; } a; a.f = f;
  unsigned r = (a.u + 0x7FFFu + ((a.u >> 16) & 1u)) >> 16;  // RNE
  return (unsigned short)r;
}

__device__ __forceinline__ float fexp2(float x) {
#if __has_builtin(__builtin_amdgcn_exp2f)
  return __builtin_amdgcn_exp2f(x);
#else
  return __exp2f(x);
#endif
}

// pack 4 fp32 -> 4 bf16 (RNE) as two dwords
__device__ __forceinline__ u32x2 pack4bf(float a, float b, float c, float d) {
  u32x2 r;
#if __has_builtin(__builtin_amdgcn_cvt_pk_bf16_f32)
  typedef __attribute__((ext_vector_type(2))) __bf16 bf2;
  union { bf2 v; unsigned u; } lo, hi;
  lo.v = __builtin_amdgcn_cvt_pk_bf16_f32(a, b);
  hi.v = __builtin_amdgcn_cvt_pk_bf16_f32(c, d);
  r[0] = lo.u; r[1] = hi.u;
#else
  r[0] = (unsigned)f2bf(a) | ((unsigned)f2bf(b) << 16);
  r[1] = (unsigned)f2bf(c) | ((unsigned)f2bf(d) << 16);
#endif
  return r;
}

typedef __attribute__((address_space(1))) const void* gvoidp;
typedef __attribute__((address_space(3))) void* lvoidp;
#define GLOADLDS16(g, l) __builtin_amdgcn_global_load_lds((gvoidp)(g), (lvoidp)(l), 16, 0, 0)

// ---------------------------------------------------------------------------
// Kernel 1 (fused transpose + QKV projection). Q rows pre-scaled by log2(e)
// so k_attn's softmax uses bare v_exp_f32 (2^x). Otherwise unchanged (proven).
__global__ __launch_bounds__(256) void k_proj(const float* __restrict__ x,
    const float* __restrict__ w1, const float* __restrict__ b1,
    const float* __restrict__ w2, const float* __restrict__ b2,
    const float* __restrict__ w3, const float* __restrict__ b3,
    unsigned short* __restrict__ Q, unsigned short* __restrict__ K,
    unsigned short* __restrict__ V) {
  __shared__ unsigned short xs[32][264];  // [n][c], +8 pad
  const int n0 = blockIdx.x * 32, b = blockIdx.y;
  const int t = threadIdx.x, lane = t & 63, wave = t >> 6;
  const int col = lane & 15, quad = lane >> 4;
  const float* xb = x + (size_t)b * NC * NSP;
#pragma unroll
  for (int p = 0; p < 8; ++p) {
    const int crow = (t >> 3) + p * 32;     // 0..255
    const int n4 = (t & 7) * 4;             // 0..28
    float4 v = *(const float4*)(xb + (size_t)crow * NSP + n0 + n4);
    xs[n4 + 0][crow] = f2bf(v.x);
    xs[n4 + 1][crow] = f2bf(v.y);
    xs[n4 + 2][crow] = f2bf(v.z);
    xs[n4 + 3][crow] = f2bf(v.w);
  }
  __syncthreads();
  const f32x4 zero4 = {0.f, 0.f, 0.f, 0.f};
  f32x4 acc[5][2];
#pragma unroll
  for (int i = 0; i < 5; ++i)
#pragma unroll
    for (int j = 0; j < 2; ++j) acc[i][j] = zero4;

  for (int kc = 0; kc < 8; ++kc) {
    short8 bf[2];
#pragma unroll
    for (int nt = 0; nt < 2; ++nt)
      bf[nt] = *(const short8*)&xs[nt * 16 + col][kc * 32 + quad * 8];
#pragma unroll
    for (int ml = 0; ml < 5; ++ml) {
      const int m0 = (wave * 5 + ml) * 16;
      const float* wbase; int roff;
      if (m0 < 32)      { wbase = w1; roff = m0; }
      else if (m0 < 64) { wbase = w2; roff = m0 - 32; }
      else              { wbase = w3; roff = m0 - 64; }
      const float* wp = wbase + (size_t)(roff + col) * NC + kc * 32 + quad * 8;
      float4 f0 = *(const float4*)wp;
      float4 f1 = *(const float4*)(wp + 4);
      short8 af;
      af[0] = f2bf(f0.x); af[1] = f2bf(f0.y); af[2] = f2bf(f0.z); af[3] = f2bf(f0.w);
      af[4] = f2bf(f1.x); af[5] = f2bf(f1.y); af[6] = f2bf(f1.z); af[7] = f2bf(f1.w);
#pragma unroll
      for (int nt = 0; nt < 2; ++nt)
        acc[ml][nt] = __builtin_amdgcn_mfma_f32_16x16x32_bf16(af, bf[nt], acc[ml][nt], 0, 0, 0);
    }
  }
#pragma unroll
  for (int ml = 0; ml < 5; ++ml) {
    const int m0 = (wave * 5 + ml) * 16;
    const float* bias;
    if (m0 < 32)      bias = b1 + m0;
    else if (m0 < 64) bias = b2 + (m0 - 32);
    else              bias = b3 + (m0 - 64);
    float bv[4];
#pragma unroll
    for (int r = 0; r < 4; ++r) bv[r] = bias[quad * 4 + r];
    if (m0 < 64) {  // Q or K : [b][n][32]
      unsigned short* dst = (m0 < 32) ? Q : K;
      const float scl = (m0 < 32) ? LOG2E : 1.0f;  // fold log2e into Q
      const int d0 = (m0 & 31) + quad * 4;
#pragma unroll
      for (int nt = 0; nt < 2; ++nt) {
        const int n = n0 + nt * 16 + col;
        us4 pk;
#pragma unroll
        for (int r = 0; r < 4; ++r) pk[r] = f2bf((acc[ml][nt][r] + bv[r]) * scl);
        *(us4*)(dst + ((size_t)b * NSP + n) * NCR + d0) = pk;
      }
    } else {        // V : [b][c][n]
      const int cbase = m0 - 64 + quad * 4;
#pragma unroll
      for (int nt = 0; nt < 2; ++nt) {
        const int n = n0 + nt * 16 + col;
#pragma unroll
        for (int r = 0; r < 4; ++r)
          V[((size_t)b * NC + cbase + r) * NSP + n] = f2bf(acc[ml][nt][r] + bv[r]);
      }
    }
  }
}

// ---------------------------------------------------------------------------
// Kernel 2 (fused attention = R8 structure + S^T scores + packed Ps writes):
// block = 48 i-rows (3 waves x 16) x 128 c-half, 192 threads.
// grid (48, 2, 8) = 768 = EXACTLY 3 blocks/CU (LDS 46.6KB), zero tail.
// Scores computed as S^T = K Q^T (operand swap): lane (col,quad) reg r holds
// S[i=col][j=mt*16+quad*4+r] -> 4 j-contiguous exps per lane -> one 8B packed
// ds_write per mt; rs is a scalar per lane (i=col), reduced with 2 shuffles.
// Ps layout/read path identical to R8. exp via bare v_exp_f32 (Q pre-scaled).
// Vs: 16B-chunk XOR swizzle (phys = logical ^ (c&7)) on the global source.
__global__ __launch_bounds__(192) void k_attn(const unsigned short* __restrict__ Q,
    const unsigned short* __restrict__ K, const unsigned short* __restrict__ V,
    const float* __restrict__ feat, const float* __restrict__ gamma,
    float* __restrict__ out) {
  __shared__ __align__(16) unsigned short smem[23296];  // 46592 B
  unsigned short* Vs = smem;            // [buf][128 c][64 j] : 2 x 8192 u16
  unsigned short* Ps = smem + 16384;    // [wave][buf][16 i][72] : 3 x 2 x 1152 u16
  const int i0 = blockIdx.x * 48, ch = blockIdx.y * 128, b = blockIdx.z;
  const int t = threadIdx.x, lane = t & 63, wave = t >> 6;  // wave 0..2
  const int col = lane & 15, quad = lane >> 4;
  const int iw = i0 + wave * 16;
  const unsigned short* Qb = Q + (size_t)b * NSP * NCR;
  const unsigned short* Kb = K + (size_t)b * NSP * NCR;
  const unsigned short* Vb = V + (size_t)b * NC * NSP;
  unsigned short* PsW = Ps + wave * 2304;  // 2 bufs x 1152

  const short8 qa = *(const short8*)(Qb + (size_t)(iw + col) * NCR + quad * 8);
  const f32x4 zero4 = {0.f, 0.f, 0.f, 0.f};
  f32x4 acc[8];
#pragma unroll
  for (int ct = 0; ct < 8; ++ct) acc[ct] = zero4;
  float rs = 0.f;  // partial row-sum for i = col (this lane's quad's j-subset)
  // staging lane map: call q covers c-rows q*8..q*8+7 (8 rows x 8 chunks of 16B);
  // lane -> row r8 = lane>>3, phys chunk pc = lane&7 holding logical chunk pc^r8.
  const int r8 = lane >> 3, pc = lane & 7, jcs = pc ^ r8;

  // ---- prologue: kb(0), stage(0) -> buf0, scores(0) -> Ps buf0
  short8 kb[4];
#pragma unroll
  for (int mt = 0; mt < 4; ++mt)
    kb[mt] = *(const short8*)(Kb + (size_t)(mt * 16 + col) * NCR + quad * 8);
#pragma unroll
  for (int cix = 0; cix < 6; ++cix) {
    const int q = wave * 6 + cix;          // 0..17; q>=16 skipped (wave-uniform)
    if (q < 16) {
      const unsigned short* g = Vb + (size_t)(ch + q * 8 + r8) * NSP + jcs * 8;
      GLOADLDS16(g, Vs + q * 512);
    }
  }
#pragma unroll
  for (int mt = 0; mt < 4; ++mt) {
    f32x4 s = __builtin_amdgcn_mfma_f32_16x16x32_bf16(kb[mt], qa, zero4, 0, 0, 0);
    const float e0 = fexp2(s[0]), e1 = fexp2(s[1]), e2 = fexp2(s[2]), e3 = fexp2(s[3]);
    rs += (e0 + e1) + (e2 + e3);
    *(u32x2*)(PsW + col * 72 + mt * 16 + quad * 4) = pack4bf(e0, e1, e2, e3);
  }

  // ---- main loop: one barrier per iteration
  for (int kc = 0; kc < 36; ++kc) {
    __syncthreads();  // Vs(kc) staged (vmcnt drained), Ps(kc) written
    const int bufc = kc & 1, bufn = bufc ^ 1;
    const int j1 = (kc + 1) * 64;
    const bool more = (kc + 1 < 36);
    if (more) {
      // kb(n+1) first (in-order vmcnt: retires before the staging loads)
#pragma unroll
      for (int mt = 0; mt < 4; ++mt)
        kb[mt] = *(const short8*)(Kb + (size_t)(j1 + mt * 16 + col) * NCR + quad * 8);
      // stage(n+1) -> Vs bufn (full PV+scores distance to drain before barrier)
#pragma unroll
      for (int cix = 0; cix < 6; ++cix) {
        const int q = wave * 6 + cix;
        if (q < 16) {
          const unsigned short* g = Vb + (size_t)(ch + q * 8 + r8) * NSP + j1 + jcs * 8;
          GLOADLDS16(g, Vs + bufn * 8192 + q * 512);
        }
      }
    }
    // PV(kc)
    const unsigned short* pwc = PsW + bufc * 1152;
    const unsigned short* vsc = Vs + bufc * 8192;
#pragma unroll
    for (int kk = 0; kk < 2; ++kk) {
      const short8 pa = *(const short8*)(pwc + col * 72 + kk * 32 + quad * 8);
#pragma unroll
      for (int ct = 0; ct < 8; ++ct) {
        const short8 vbf = *(const short8*)(vsc + (ct * 16 + col) * 64 +
                                            (((kk * 4 + quad) ^ (col & 7)) * 8));
        acc[ct] = __builtin_amdgcn_mfma_f32_16x16x32_bf16(pa, vbf, acc[ct], 0, 0, 0);
      }
    }
    if (more) {
      // scores(n+1) -> Ps bufn  (S^T: lane holds 4 j-contiguous elems of row col)
      unsigned short* pwn = PsW + bufn * 1152;
#pragma unroll
      for (int mt = 0; mt < 4; ++mt) {
        f32x4 s = __builtin_amdgcn_mfma_f32_16x16x32_bf16(kb[mt], qa, zero4, 0, 0, 0);
        const float e0 = fexp2(s[0]), e1 = fexp2(s[1]), e2 = fexp2(s[2]), e3 = fexp2(s[3]);
        rs += (e0 + e1) + (e2 + e3);
        *(u32x2*)(pwn + col * 72 + mt * 16 + quad * 4) = pack4bf(e0, e1, e2, e3);
      }
    }
  }

  // ---- l: sum the 4 quads of each col (full row-sum for i = col), then
  // redistribute to D-layout rows (i = quad*4 + r) for the epilogue.
  rs += __shfl_xor(rs, 16, 64);
  rs += __shfl_xor(rs, 32, 64);
  const float g = gamma[0];
  float rinv[4];
#pragma unroll
  for (int r = 0; r < 4; ++r) rinv[r] = g / __shfl(rs, quad * 4 + r, 64);

  // ---- epilogue: float4 over r (i-contiguous), 64B segments
  const float* fb = feat + (size_t)b * NC * NSP;
  float* ob = out + (size_t)b * NC * NSP;
#pragma unroll
  for (int ct = 0; ct < 8; ++ct) {
    const size_t a0 = (size_t)(ch + ct * 16 + col) * NSP + iw + quad * 4;
    float4 f = *(const float4*)(fb + a0);
    float4 o;
    o.x = acc[ct][0] * rinv[0] + f.x;
    o.y = acc[ct][1] * rinv[1] + f.y;
    o.z = acc[ct][2] * rinv[2] + f.z;
    o.w = acc[ct][3] * rinv[3] + f.w;
    *(float4*)(ob + a0) = o;
  }
}

// ---------------------------------------------------------------------------
// Workspace layout (bytes), total 11,796,480 (~11.3 MB):
//   Q : [0, 1179648)            bf16 [8][2304][32]   (pre-scaled by log2e)
//   K : [1179648, 2359296)      bf16 [8][2304][32]
//   V : [2359296, 11796480)     bf16 [8][256][2304]
#define OFF_Q  0UL
#define OFF_K  1179648UL
#define OFF_V  2359296UL

extern "C" void kernel_launch(void* const* d_in, const int* in_sizes, int n_in,
                              void* d_out, int out_size, void* d_ws, size_t ws_size,
                              hipStream_t stream) {
  const float* feat  = (const float*)d_in[0];
  const float* w1    = (const float*)d_in[1];
  const float* b1    = (const float*)d_in[2];
  const float* w2    = (const float*)d_in[3];
  const float* b2    = (const float*)d_in[4];
  const float* w3    = (const float*)d_in[5];
  const float* b3    = (const float*)d_in[6];
  const float* gamma = (const float*)d_in[7];
  float* out = (float*)d_out;
  char* ws = (char*)d_ws;
  unsigned short* Q = (unsigned short*)(ws + OFF_Q);
  unsigned short* K = (unsigned short*)(ws + OFF_K);
  unsigned short* V = (unsigned short*)(ws + OFF_V);

  hipLaunchKernelGGL(k_proj, dim3(72, NB), dim3(256), 0, stream,
                     feat, w1, b1, w2, b2, w3, b3, Q, K, V);
  hipLaunchKernelGGL(k_attn, dim3(48, 2, NB), dim3(192), 0, stream,
                     Q, K, V, feat, gamma, out);
}